// Round 2
// baseline (648.620 us; speedup 1.0000x reference)
//
#include <hip/hip_runtime.h>
#include <hip/hip_bf16.h>
#include <math.h>

// Problem constants (from reference setup_inputs):
//   N = 100000 nodes, E = 3.2M edges, F_in = 128, H = 16, C = 16
// Derived at launch from in_sizes to be safe.
// NOTE: harness delivers integer inputs as int32 (edge_index int64 -> int*).

#define F_IN 128
#define H 16   // hidden = classes = 16

__global__ void init_deg_kernel(float* deg, int n) {
    int i = blockIdx.x * blockDim.x + threadIdx.x;
    if (i < n) deg[i] = 1.0f;  // self-loop contributes 1 to every node's degree
}

__global__ void deg_accum_kernel(const int* __restrict__ dst, float* deg, int E) {
    int e = blockIdx.x * blockDim.x + threadIdx.x;
    if (e < E) atomicAdd(&deg[dst[e]], 1.0f);
}

__global__ void rsqrt_kernel(float* deg, int n) {
    int i = blockIdx.x * blockDim.x + threadIdx.x;
    if (i < n) deg[i] = rsqrtf(deg[i]);  // deg >= 1 always (self-loop)
}

// u[i][j] = dinv[i] * sum_k x[i][k] * W1[k][j]
// block = 256 threads = 16 rows x 16 cols; W1 (128x16) staged in LDS.
__global__ void xw1_kernel(const float* __restrict__ x, const float* __restrict__ W1,
                           const float* __restrict__ dinv, float* __restrict__ u, int n) {
    __shared__ float sW1[F_IN * H];
    for (int t = threadIdx.x; t < F_IN * H; t += blockDim.x) sW1[t] = W1[t];
    __syncthreads();

    int row = blockIdx.x * 16 + (threadIdx.x >> 4);
    int j = threadIdx.x & 15;
    if (row >= n) return;

    const float* xr = x + (size_t)row * F_IN;
    float acc = 0.0f;
#pragma unroll 8
    for (int k = 0; k < F_IN; k++) acc += xr[k] * sW1[k * H + j];
    u[row * H + j] = dinv[row] * acc;
}

// one (edge, channel) pair per thread: agg[dst][j] += u[src][j]
__global__ void scatter16_kernel(const int* __restrict__ src, const int* __restrict__ dst,
                                 const float* __restrict__ u, float* __restrict__ agg, int E) {
    int t = blockIdx.x * blockDim.x + threadIdx.x;
    int e = t >> 4;
    int j = t & 15;
    if (e < E) {
        int s = src[e];
        int d = dst[e];
        atomicAdd(&agg[d * H + j], u[s * H + j]);
    }
}

// h1 = relu(dinv*(agg+u) + b1); then u2 = dinv*(h1 @ W2), overwriting u.
__global__ void finalize1_kernel(const float* __restrict__ agg, float* __restrict__ u,
                                 const float* __restrict__ dinv, const float* __restrict__ b1,
                                 const float* __restrict__ W2, int n) {
    __shared__ float sW2[H * H];
    __shared__ float sb1[H];
    if (threadIdx.x < H * H) sW2[threadIdx.x] = W2[threadIdx.x];
    if (threadIdx.x < H) sb1[threadIdx.x] = b1[threadIdx.x];
    __syncthreads();

    int row = blockIdx.x * 16 + (threadIdx.x >> 4);
    int j = threadIdx.x & 15;
    if (row >= n) return;

    float di = dinv[row];
    float h = di * (agg[row * H + j] + u[row * H + j]) + sb1[j];
    h = fmaxf(h, 0.0f);

    // 16-wide matmul via shuffles (4 rows share one 64-lane wave)
    float acc = 0.0f;
#pragma unroll
    for (int k = 0; k < H; k++) {
        float hk = __shfl(h, k, 16);
        acc += hk * sW2[k * H + j];
    }
    u[row * H + j] = di * acc;
}

// v = dinv*(agg+u) + b2; out = log_softmax(v) rowwise over 16.
__global__ void finalize2_kernel(const float* __restrict__ agg, const float* __restrict__ u,
                                 const float* __restrict__ dinv, const float* __restrict__ b2,
                                 float* __restrict__ out, int n) {
    __shared__ float sb2[H];
    if (threadIdx.x < H) sb2[threadIdx.x] = b2[threadIdx.x];
    __syncthreads();

    int row = blockIdx.x * 16 + (threadIdx.x >> 4);
    int j = threadIdx.x & 15;
    if (row >= n) return;

    float di = dinv[row];
    float v = di * (agg[row * H + j] + u[row * H + j]) + sb2[j];

    // max over 16 lanes
    float m = v;
#pragma unroll
    for (int off = 8; off >= 1; off >>= 1) m = fmaxf(m, __shfl_xor(m, off, 16));
    float ex = __expf(v - m);
    float s = ex;
#pragma unroll
    for (int off = 8; off >= 1; off >>= 1) s += __shfl_xor(s, off, 16);

    out[row * H + j] = v - m - __logf(s);
}

extern "C" void kernel_launch(void* const* d_in, const int* in_sizes, int n_in,
                              void* d_out, int out_size, void* d_ws, size_t ws_size,
                              hipStream_t stream) {
    const float* x = (const float*)d_in[0];
    const int* edge_index = (const int*)d_in[1];   // int64 in reference -> int32 from harness
    const float* W1 = (const float*)d_in[2];
    const float* b1 = (const float*)d_in[3];
    const float* W2 = (const float*)d_in[4];
    const float* b2 = (const float*)d_in[5];
    float* out = (float*)d_out;

    const int N = in_sizes[0] / F_IN;        // 100000
    const int E = in_sizes[1] / 2;           // 3200000
    const int* src = edge_index;             // row 0
    const int* dst = edge_index + E;         // row 1

    // Workspace layout (floats): deg[N] | u[N*16] | agg[N*16]  (~13.2 MB)
    float* deg = (float*)d_ws;               // becomes dinv in place
    float* u   = deg + N;
    float* agg = u + (size_t)N * H;

    // --- degree / dinv ---
    hipMemsetAsync(agg, 0, (size_t)N * H * sizeof(float), stream);
    init_deg_kernel<<<(N + 255) / 256, 256, 0, stream>>>(deg, N);
    deg_accum_kernel<<<(E + 255) / 256, 256, 0, stream>>>(dst, deg, E);
    rsqrt_kernel<<<(N + 255) / 256, 256, 0, stream>>>(deg, N);

    // --- layer 1 ---
    xw1_kernel<<<(N + 15) / 16, 256, 0, stream>>>(x, W1, deg, u, N);
    {
        long long tot = (long long)E * H;
        scatter16_kernel<<<(int)((tot + 255) / 256), 256, 0, stream>>>(src, dst, u, agg, E);
    }
    finalize1_kernel<<<(N + 15) / 16, 256, 0, stream>>>(agg, u, deg, b1, W2, N);

    // --- layer 2 ---
    hipMemsetAsync(agg, 0, (size_t)N * H * sizeof(float), stream);
    {
        long long tot = (long long)E * H;
        scatter16_kernel<<<(int)((tot + 255) / 256), 256, 0, stream>>>(src, dst, u, agg, E);
    }
    finalize2_kernel<<<(N + 15) / 16, 256, 0, stream>>>(agg, u, deg, b2, out, N);
}